// Round 7
// baseline (661.904 us; speedup 1.0000x reference)
//
#include <hip/hip_runtime.h>
#include <hip/hip_bf16.h>

#define Vn   196608
#define NNZn 1769472
#define Bn   4
#define Pn   64
#define Qn   64
#define VPn  (Vn*Pn)

typedef __hip_bfloat16 bf16;
typedef __attribute__((ext_vector_type(8))) short bf16x8;
typedef __attribute__((ext_vector_type(4))) float f32x4;
typedef __attribute__((ext_vector_type(4))) unsigned int u32x4;

__device__ inline short f2bs(float f){
  __hip_bfloat16 h = __float2bfloat16(f);
  return *(short*)&h;
}
__device__ inline float bs2f(unsigned short s){
  return __uint_as_float(((unsigned)s)<<16);
}
__device__ inline float lo16(unsigned u){ return __uint_as_float(u<<16); }
__device__ inline float hi16(unsigned u){ return __uint_as_float(u & 0xffff0000u); }

// ---------------- CSR build (counting sort) ----------------

__global__ void k_zero(unsigned* __restrict__ p, int n){
  int i = blockIdx.x*blockDim.x + threadIdx.x;
  if(i<n) p[i]=0u;
}

// 4 edges per thread: 4 independent atomic chains in flight (latency ILP).
__global__ void k_hist(const int* __restrict__ rows, unsigned* __restrict__ counts){
  int i = (blockIdx.x*256 + threadIdx.x)*4;    // grid covers NNZ exactly
  const int4 r = *(const int4*)(rows + i);
  atomicAdd(&counts[r.x], 1u);
  atomicAdd(&counts[r.y], 1u);
  atomicAdd(&counts[r.z], 1u);
  atomicAdd(&counts[r.w], 1u);
}

__global__ __launch_bounds__(1024) void k_scan_block(const unsigned* __restrict__ counts,
                                                     unsigned* __restrict__ incl,
                                                     unsigned* __restrict__ bsums){
  __shared__ unsigned s[1024];
  const int tid = threadIdx.x;
  const int gid = blockIdx.x*1024 + tid;
  s[tid] = counts[gid];
  __syncthreads();
  for(int off=1; off<1024; off<<=1){
    unsigned v = (tid>=off) ? s[tid-off] : 0u;
    __syncthreads();
    s[tid] += v;
    __syncthreads();
  }
  incl[gid] = s[tid];
  if(tid==1023) bsums[blockIdx.x] = s[1023];
}

__global__ void k_scan_top(unsigned* __restrict__ bs){
  __shared__ unsigned t[192];
  const int i = threadIdx.x;                 // 256 threads
  if(i<192) t[i]=bs[i];
  __syncthreads();
  for(int off=1; off<192; off<<=1){
    unsigned v = (i>=off && i<192) ? t[i-off] : 0u;
    __syncthreads();
    if(i<192) t[i] += v;
    __syncthreads();
  }
  if(i<192) bs[i] = (i==0) ? 0u : t[i-1];   // exclusive
}

__global__ void k_scan_add(const unsigned* __restrict__ counts, unsigned* __restrict__ incl,
                           const unsigned* __restrict__ boffs,
                           unsigned* __restrict__ rstart, unsigned* __restrict__ cursor){
  int i = blockIdx.x*blockDim.x + threadIdx.x;   // grid covers V exactly
  unsigned e = incl[i] + boffs[i>>10];
  incl[i] = e;
  unsigned st = e - counts[i];
  rstart[i] = st;
  cursor[i] = st;
}

// 4 edges per thread: vectorized reads + 4 independent atomic+store chains.
__global__ void k_scatter(const float* __restrict__ vals, const int* __restrict__ rows,
                          const int* __restrict__ cols, unsigned* __restrict__ cursor,
                          int2* __restrict__ meta){
  int i = (blockIdx.x*256 + threadIdx.x)*4;    // grid covers NNZ exactly
  const int4   r = *(const int4*)(rows + i);
  const int4   c = *(const int4*)(cols + i);
  const float4 v = *(const float4*)(vals + i);
  const unsigned p0 = atomicAdd(&cursor[r.x], 1u);
  const unsigned p1 = atomicAdd(&cursor[r.y], 1u);
  const unsigned p2 = atomicAdd(&cursor[r.z], 1u);
  const unsigned p3 = atomicAdd(&cursor[r.w], 1u);
  int2 m0; m0.x=c.x; m0.y=__float_as_int(v.x); meta[p0]=m0;
  int2 m1; m1.x=c.y; m1.y=__float_as_int(v.y); meta[p1]=m1;
  int2 m2; m2.x=c.z; m2.y=__float_as_int(v.z); meta[p2]=m2;
  int2 m3; m3.x=c.w; m3.y=__float_as_int(v.w); meta[p3]=m3;
}

// ---------------- x -> bf16 x0c, stored INSIDE d_out ----------------
// x0c piece h (h=b>>1) of row v lives at shorts offset (h*Vn + v)*128, i.e.
// exactly the out-fp32 bytes of batch h, row v -- each gemm block's x0 reads
// are inside its own out-write region (race-free with an intra-block barrier).

__global__ void k_cvt(const float* __restrict__ x, short* __restrict__ x0c){
  const int i = blockIdx.x*256 + threadIdx.x;    // V*256/4 threads
  const int o = i*4;
  const int v = o>>8, bp = o&255;
  const int h = bp>>7, w7 = bp&127;
  const int b = (h<<1) + (w7>>6), p = w7&63;
  const float4 f = *(const float4*)(x + (size_t)b*VPn + (size_t)v*64 + p);
  ushort4 u;
  u.x = (unsigned short)f2bs(f.x); u.y = (unsigned short)f2bs(f.y);
  u.z = (unsigned short)f2bs(f.z); u.w = (unsigned short)f2bs(f.w);
  *(ushort4*)(x0c + ((size_t)h*Vn + v)*128 + w7) = u;
}

// ---------------- SpMM: TWO rows per wave (one per half-wave) ---------------
// Lane sub=lane&31 covers 8 consecutive elems (16B) of its half's row.
// Depth-4 rotate pipeline with NAMED slot registers (R3-proven codegen);
// each slot's one dwordx4 load fetches 1024B (both rows) -> 2x in-flight.
// Per-lane predication only (cndmask); loop bound = max(n0,n1), uniform.
// Source addressing: elem e of row c at src + c*SROW + (e>>7)*PSTR + (e&127).

template<int SROW, size_t PSTR>
__global__ __launch_bounds__(256) void k_spmm(const short* __restrict__ src,
                          const int2* __restrict__ meta,
                          const unsigned* __restrict__ rstart, const unsigned* __restrict__ rend,
                          short* __restrict__ dst){
  const int tid = threadIdx.x;
  const int lane = tid & 63;
  const int half = lane >> 5, sub = lane & 31;
  const int vbase = blockIdx.x*8 + (tid>>6)*2;
  const unsigned sA = rstart[vbase],   eA = rend[vbase];
  const unsigned sB = rstart[vbase+1], eB = rend[vbase+1];
  const int nA = (int)(eA - sA), nB = (int)(eB - sB);
  const int nmax = (nA > nB) ? nA : nB;
  const unsigned s = half ? sB : sA;
  const int n = half ? nB : nA;
  const size_t off = (size_t)(sub>>4)*PSTR + (size_t)((sub&15)*8);
  float a0=0,a1=0,a2=0,a3=0,a4=0,a5=0,a6=0,a7=0;

#define STAGE(U,W,I) { int c_=0; float wv_=0.f; \
    if((I) < n){ const int2 m_ = meta[s+(unsigned)(I)]; c_=m_.x; wv_=__int_as_float(m_.y);} \
    W = wv_; U = *(const u32x4*)(src + (size_t)c_*SROW + off); }
#define CONSUME(U,W) { \
    a0=fmaf(W,lo16(U[0]),a0); a1=fmaf(W,hi16(U[0]),a1); \
    a2=fmaf(W,lo16(U[1]),a2); a3=fmaf(W,hi16(U[1]),a3); \
    a4=fmaf(W,lo16(U[2]),a4); a5=fmaf(W,hi16(U[2]),a5); \
    a6=fmaf(W,lo16(U[3]),a6); a7=fmaf(W,hi16(U[3]),a7); }

  if(nmax > 0){
    u32x4 u0,u1,u2,u3; float w0,w1,w2,w3;
    STAGE(u0,w0,0) STAGE(u1,w1,1) STAGE(u2,w2,2) STAGE(u3,w3,3)
    int rem = nmax - 4;
    int j = 4;
    while(rem > 0){
      const u32x4 p0=u0, p1=u1, p2=u2, p3=u3;
      const float q0=w0, q1=w1, q2=w2, q3=w3;
      STAGE(u0,w0,j) STAGE(u1,w1,j+1) STAGE(u2,w2,j+2) STAGE(u3,w3,j+3)
      CONSUME(p0,q0) CONSUME(p1,q1) CONSUME(p2,q2) CONSUME(p3,q3)
      rem -= 4; j += 4;
    }
    CONSUME(u0,w0) CONSUME(u1,w1) CONSUME(u2,w2) CONSUME(u3,w3)
  }
#undef STAGE
#undef CONSUME

  unsigned r0 = ((unsigned)(unsigned short)f2bs(a1)<<16) | (unsigned)(unsigned short)f2bs(a0);
  unsigned r1 = ((unsigned)(unsigned short)f2bs(a3)<<16) | (unsigned)(unsigned short)f2bs(a2);
  unsigned r2 = ((unsigned)(unsigned short)f2bs(a5)<<16) | (unsigned)(unsigned short)f2bs(a4);
  unsigned r3 = ((unsigned)(unsigned short)f2bs(a7)<<16) | (unsigned)(unsigned short)f2bs(a6);
  u32x4 o; o[0]=r0; o[1]=r1; o[2]=r2; o[3]=r3;
  *(u32x4*)(dst + (size_t)(vbase+half)*256 + sub*8) = o;
}

// ---------------- combined weights: wcb[q][k3], k3 = part*64 + p ----------------
// part0: W0-W2, part1: W1, part2: 2*W2, where Wk[p][q] = wf[(3p+k)*64+q].

__global__ void k_prepw(const float* __restrict__ wf, short* __restrict__ wcb){
  int idx = blockIdx.x*256 + threadIdx.x;      // 12288 total
  int q = idx/192, rem = idx%192, part = rem>>6, p = rem&63;
  float w;
  if(part==0)      w = wf[(3*p+0)*64+q] - wf[(3*p+2)*64+q];
  else if(part==1) w = wf[(3*p+1)*64+q];
  else             w = 2.0f*wf[(3*p+2)*64+q];
  wcb[idx] = f2bs(w);
}

// ---------------- MFMA GEMM epilogue ----------------
// out[b,v,q] = bias[q] + sum_k3 A[v-row,k3] * Wc[k3,q]
// A parts: [0,64): x0 (bf16, from x0c in d_out); [64,128): x1; [128,192): y.
// mfma_f32_16x16x32_bf16: A row=l&15, k=8*(l>>4)+i; C/D col=l&15, row=4*(l>>4)+reg.
// 2-deep phase pipeline: next phase's A-loads issue during current MFMAs.

#define WTP 200   // LDS pitch in bf16 elems: bank stride 4 -> conflict-free

#define LOADA(dst, cc) { \
  const int part_ = (cc)>>1, ko_ = ((cc)&1)*32; \
  if(part_==0){ \
    const short* sp = x0 + ((size_t)(w>>1)*Vn + v0 + r)*128 + (w&1)*64 + ko_ + 8*g; \
    _Pragma("unroll") for(int m_=0;m_<4;++m_) dst[m_] = *(const bf16x8*)(sp + (size_t)m_*16*128); \
  } else { \
    const short* sp = (part_==1 ? x1 : y) + ((v0 + r)*256 + w*64 + ko_ + 8*g); \
    _Pragma("unroll") for(int m_=0;m_<4;++m_) dst[m_] = *(const bf16x8*)(sp + (size_t)m_*16*256); \
  } }

__global__ __launch_bounds__(256) void k_gemm_mfma(const short* __restrict__ x0,
                      const short* __restrict__ x1, const short* __restrict__ y,
                      const short* __restrict__ wcb, const float* __restrict__ bias,
                      float* __restrict__ out){
  __shared__ short WT[64*WTP];    // 25600 B, [q][k3] padded
  const int t = threadIdx.x;
  for(int idx=t; idx<1536; idx+=256){
    const int row = idx/24, ch = idx%24;
    *(uint4*)&WT[row*WTP + ch*8] = ((const uint4*)wcb)[row*24 + ch];
  }
  const int w = t>>6;          // wave id = batch b
  const int l = t&63, r = l&15, g = l>>4;
  const size_t v0 = (size_t)blockIdx.x*64;
  f32x4 acc[4][4] = {};
  bf16x8 aC[4], aN[4];
  LOADA(aC, 0);
  __syncthreads();

#pragma unroll
  for(int c=0; c<6; ++c){
    if(c < 5) LOADA(aN, c+1);
    const int part = c>>1, ko = (c&1)*32;
    const int kw = part*64 + ko + 8*g;
#pragma unroll
    for(int n=0;n<4;++n){
      const bf16x8 bfr = *(const bf16x8*)&WT[(n*16+r)*WTP + kw];
#pragma unroll
      for(int m=0;m<4;++m)
        acc[m][n] = __builtin_amdgcn_mfma_f32_16x16x32_bf16(aC[m], bfr, acc[m][n], 0, 0, 0);
    }
    if(c < 5){
#pragma unroll
      for(int m=0;m<4;++m) aC[m] = aN[m];
    }
  }

  __syncthreads();   // all x0c reads (in d_out) done before overwriting with out

  float* ob = out + (size_t)w*Vn*64 + v0*64;
#pragma unroll
  for(int n=0;n<4;++n){
    const float bq = bias[n*16+r];
#pragma unroll
    for(int m=0;m<4;++m){
#pragma unroll
      for(int reg=0;reg<4;++reg){
        const int row = m*16 + g*4 + reg;
        ob[(size_t)row*64 + n*16 + r] = acc[m][n][reg] + bq;
      }
    }
  }
}

// ---------------- launch ----------------

extern "C" void kernel_launch(void* const* d_in, const int* in_sizes, int n_in,
                              void* d_out, int out_size, void* d_ws, size_t ws_size,
                              hipStream_t stream){
  const float* lap_vals = (const float*)d_in[0];
  const float* x        = (const float*)d_in[1];
  const float* weight   = (const float*)d_in[2];
  const float* bias     = (const float*)d_in[3];
  const int*   lap_rows = (const int*)d_in[4];
  const int*   lap_cols = (const int*)d_in[5];
  float* out = (float*)d_out;
  short* x0c = (short*)d_out;   // bf16 x0 staged inside the output buffer

  char* w = (char*)d_ws;
  short* x1b = (short*)w;          w += (size_t)Vn*256*sizeof(short);
  short* yb  = (short*)w;          w += (size_t)Vn*256*sizeof(short);
  int2* meta = (int2*)w;           w += (size_t)NNZn*8;
  unsigned* counts = (unsigned*)w; w += (size_t)Vn*4;
  unsigned* cursor = (unsigned*)w; w += (size_t)Vn*4;
  unsigned* rstart = (unsigned*)w; w += (size_t)Vn*4;
  unsigned* rend   = (unsigned*)w; w += (size_t)Vn*4;
  unsigned* bsums  = (unsigned*)w; w += 1024;
  short* wcb = (short*)w;          w += 12288*sizeof(short);

  k_zero<<<Vn/256, 256, 0, stream>>>(counts, Vn);
  k_hist<<<NNZn/1024, 256, 0, stream>>>(lap_rows, counts);
  k_scan_block<<<192, 1024, 0, stream>>>(counts, rend, bsums);
  k_scan_top<<<1, 256, 0, stream>>>(bsums);
  k_scan_add<<<Vn/256, 256, 0, stream>>>(counts, rend, bsums, rstart, cursor);
  k_scatter<<<NNZn/1024, 256, 0, stream>>>(lap_vals, lap_rows, lap_cols, cursor, meta);
  k_prepw<<<48, 256, 0, stream>>>(weight, wcb);
  k_cvt<<<Vn*64/256, 256, 0, stream>>>(x, x0c);

  // x1 = L @ x0   (gather from x0c: piece-split rows, 2 x 256B segments)
  k_spmm<128, (size_t)Vn*128><<<Vn/8, 256, 0, stream>>>(x0c, meta, rstart, rend, x1b);
  // y = L @ x1    (gather from x1b: flat rows, contiguous 512B)
  k_spmm<256, 128><<<Vn/8, 256, 0, stream>>>(x1b, meta, rstart, rend, yb);

  k_gemm_mfma<<<Vn/64, 256, 0, stream>>>(x0c, x1b, yb, wcb, bias, out);
}

// Round 8
// 610.032 us; speedup vs baseline: 1.0850x; 1.0850x over previous
//
#include <hip/hip_runtime.h>
#include <hip/hip_bf16.h>

#define Vn   196608
#define NNZn 1769472
#define Bn   4
#define Pn   64
#define Qn   64
#define VPn  (Vn*Pn)

typedef __hip_bfloat16 bf16;
typedef __attribute__((ext_vector_type(8))) short bf16x8;
typedef __attribute__((ext_vector_type(4))) float f32x4;
typedef __attribute__((ext_vector_type(4))) unsigned int u32x4;

__device__ inline short f2bs(float f){
  __hip_bfloat16 h = __float2bfloat16(f);
  return *(short*)&h;
}
__device__ inline float lo16(unsigned u){ return __uint_as_float(u<<16); }
__device__ inline float hi16(unsigned u){ return __uint_as_float(u & 0xffff0000u); }

// ---------------- CSR build (counting sort) ----------------

__global__ void k_zero(unsigned* __restrict__ p, int n){
  int i = blockIdx.x*blockDim.x + threadIdx.x;
  if(i<n) p[i]=0u;
}

// ---- fused pre-pass: hist (latency-bound) + cvt (streaming) + prepw -------
// Block-uniform role selection; hist blocks interleaved 1-in-15 so every CU
// holds a mix of waiting-on-atomic waves and streaming waves.
// hist: 1728 blocks x 4 edges/thread.  cvt: 24576 blocks x 8 floats/thread.
// prepw: 48 blocks.  grid = 1728*15 + 432 = 26352.
// x0c piece h (h=b>>1) of row v lives at shorts offset (h*Vn + v)*128 inside
// d_out (= out batch h, row v); gemm blocks only read their own write region.

__global__ void k_pre(const int* __restrict__ rows, unsigned* __restrict__ counts,
                      const float* __restrict__ x, short* __restrict__ x0c,
                      const float* __restrict__ wf, short* __restrict__ wcb){
  const int bid = blockIdx.x;
  int h=-1, f=-1;
  if(bid < 25920){
    if(bid%15==0) h = bid/15;
    else          f = 14*(bid/15) + (bid%15) - 1;
  } else {
    f = 24192 + (bid - 25920);
  }
  if(h >= 0){                      // ---- hist: 4 independent atomic chains
    const int i = (h*256 + threadIdx.x)*4;
    const int4 r = *(const int4*)(rows + i);
    atomicAdd(&counts[r.x], 1u);
    atomicAdd(&counts[r.y], 1u);
    atomicAdd(&counts[r.z], 1u);
    atomicAdd(&counts[r.w], 1u);
  } else if(f < 24576){            // ---- cvt: 8 floats -> 8 bf16 per thread
    const int i = f*256 + threadIdx.x;
    const int o = i*8;
    const int v = o>>8, bp = o&255;
    const int hh = bp>>7, w7 = bp&127;
    const int b = (hh<<1) + (w7>>6), p = w7&63;
    const float* xp = x + (size_t)b*VPn + (size_t)v*64 + p;
    const float4 f0 = *(const float4*)xp;
    const float4 f1 = *(const float4*)(xp+4);
    unsigned r0 = ((unsigned)(unsigned short)f2bs(f0.y)<<16) | (unsigned)(unsigned short)f2bs(f0.x);
    unsigned r1 = ((unsigned)(unsigned short)f2bs(f0.w)<<16) | (unsigned)(unsigned short)f2bs(f0.z);
    unsigned r2 = ((unsigned)(unsigned short)f2bs(f1.y)<<16) | (unsigned)(unsigned short)f2bs(f1.x);
    unsigned r3 = ((unsigned)(unsigned short)f2bs(f1.w)<<16) | (unsigned)(unsigned short)f2bs(f1.z);
    u32x4 u; u[0]=r0; u[1]=r1; u[2]=r2; u[3]=r3;
    *(u32x4*)(x0c + ((size_t)hh*Vn + v)*128 + w7) = u;
  } else {                         // ---- prepw: combined weights wcb[q][192]
    const int idx = (f - 24576)*256 + threadIdx.x;   // 12288 total
    const int q = idx/192, rem = idx%192, part = rem>>6, p = rem&63;
    float w;
    if(part==0)      w = wf[(3*p+0)*64+q] - wf[(3*p+2)*64+q];
    else if(part==1) w = wf[(3*p+1)*64+q];
    else             w = 2.0f*wf[(3*p+2)*64+q];
    wcb[idx] = f2bs(w);
  }
}

__global__ __launch_bounds__(1024) void k_scan_block(const unsigned* __restrict__ counts,
                                                     unsigned* __restrict__ incl,
                                                     unsigned* __restrict__ bsums){
  __shared__ unsigned s[1024];
  const int tid = threadIdx.x;
  const int gid = blockIdx.x*1024 + tid;
  s[tid] = counts[gid];
  __syncthreads();
  for(int off=1; off<1024; off<<=1){
    unsigned v = (tid>=off) ? s[tid-off] : 0u;
    __syncthreads();
    s[tid] += v;
    __syncthreads();
  }
  incl[gid] = s[tid];
  if(tid==1023) bsums[blockIdx.x] = s[1023];
}

__global__ void k_scan_top(unsigned* __restrict__ bs){
  __shared__ unsigned t[192];
  const int i = threadIdx.x;                 // 256 threads
  if(i<192) t[i]=bs[i];
  __syncthreads();
  for(int off=1; off<192; off<<=1){
    unsigned v = (i>=off && i<192) ? t[i-off] : 0u;
    __syncthreads();
    if(i<192) t[i] += v;
    __syncthreads();
  }
  if(i<192) bs[i] = (i==0) ? 0u : t[i-1];   // exclusive
}

__global__ void k_scan_add(const unsigned* __restrict__ counts, unsigned* __restrict__ incl,
                           const unsigned* __restrict__ boffs,
                           unsigned* __restrict__ rstart, unsigned* __restrict__ cursor){
  int i = blockIdx.x*blockDim.x + threadIdx.x;   // grid covers V exactly
  unsigned e = incl[i] + boffs[i>>10];
  incl[i] = e;
  unsigned st = e - counts[i];
  rstart[i] = st;
  cursor[i] = st;
}

// 1 edge/thread (R5-proven shape: max wave count, best atomic pipelining).
__global__ void k_scatter(const float* __restrict__ vals, const int* __restrict__ rows,
                          const int* __restrict__ cols, unsigned* __restrict__ cursor,
                          int2* __restrict__ meta){
  int i = blockIdx.x*blockDim.x + threadIdx.x;   // grid covers NNZ exactly
  int r = rows[i];
  unsigned pos = atomicAdd(&cursor[r], 1u);
  int2 m; m.x = cols[i]; m.y = __float_as_int(vals[i]);
  meta[pos] = m;
}

// ---------------- SpMM1: TWO rows per wave (one per half-wave) --------------
// x1 = L @ x0 gathered from x0c (piece layout: SROW=128, PSTR=Vn*128).
// Depth-4 rotate pipeline with NAMED slot registers.

#define SP_STAGE(U,W,I) { int c_=0; float wv_=0.f; \
    if((I) < n){ const int2 m_ = meta[s+(unsigned)(I)]; c_=m_.x; wv_=__int_as_float(m_.y);} \
    W = wv_; U = *(const u32x4*)(src + (size_t)c_*SROW + off); }
#define SP_CONSUME(U,W) { \
    a0=fmaf(W,lo16(U[0]),a0); a1=fmaf(W,hi16(U[0]),a1); \
    a2=fmaf(W,lo16(U[1]),a2); a3=fmaf(W,hi16(U[1]),a3); \
    a4=fmaf(W,lo16(U[2]),a4); a5=fmaf(W,hi16(U[2]),a5); \
    a6=fmaf(W,lo16(U[3]),a6); a7=fmaf(W,hi16(U[3]),a7); }
#define SP_BODY \
  float a0=0,a1=0,a2=0,a3=0,a4=0,a5=0,a6=0,a7=0; \
  if(nmax > 0){ \
    u32x4 u0,u1,u2,u3; float w0,w1,w2,w3; \
    SP_STAGE(u0,w0,0) SP_STAGE(u1,w1,1) SP_STAGE(u2,w2,2) SP_STAGE(u3,w3,3) \
    int rem = nmax - 4; \
    int j = 4; \
    while(rem > 0){ \
      const u32x4 p0=u0, p1=u1, p2=u2, p3=u3; \
      const float q0=w0, q1=w1, q2=w2, q3=w3; \
      SP_STAGE(u0,w0,j) SP_STAGE(u1,w1,j+1) SP_STAGE(u2,w2,j+2) SP_STAGE(u3,w3,j+3) \
      SP_CONSUME(p0,q0) SP_CONSUME(p1,q1) SP_CONSUME(p2,q2) SP_CONSUME(p3,q3) \
      rem -= 4; j += 4; \
    } \
    SP_CONSUME(u0,w0) SP_CONSUME(u1,w1) SP_CONSUME(u2,w2) SP_CONSUME(u3,w3) \
  } \
  unsigned r0 = ((unsigned)(unsigned short)f2bs(a1)<<16) | (unsigned)(unsigned short)f2bs(a0); \
  unsigned r1 = ((unsigned)(unsigned short)f2bs(a3)<<16) | (unsigned)(unsigned short)f2bs(a2); \
  unsigned r2 = ((unsigned)(unsigned short)f2bs(a5)<<16) | (unsigned)(unsigned short)f2bs(a4); \
  unsigned r3 = ((unsigned)(unsigned short)f2bs(a7)<<16) | (unsigned)(unsigned short)f2bs(a6); \
  u32x4 ov; ov[0]=r0; ov[1]=r1; ov[2]=r2; ov[3]=r3;

template<int SROW, size_t PSTR>
__global__ __launch_bounds__(256) void k_spmm(const short* __restrict__ src,
                          const int2* __restrict__ meta,
                          const unsigned* __restrict__ rstart, const unsigned* __restrict__ rend,
                          short* __restrict__ dst){
  const int tid = threadIdx.x;
  const int lane = tid & 63;
  const int half = lane >> 5, sub = lane & 31;
  const int vbase = blockIdx.x*8 + (tid>>6)*2;
  const unsigned sA = rstart[vbase],   sB = rstart[vbase+1];
  const int nA = (int)(rend[vbase]-sA), nB = (int)(rend[vbase+1]-sB);
  const int nmax = (nA > nB) ? nA : nB;
  const unsigned s = half ? sB : sA;
  const int n = half ? nB : nA;
  const size_t off = (size_t)(sub>>4)*PSTR + (size_t)((sub&15)*8);
  SP_BODY
  *(u32x4*)(dst + (size_t)(vbase+half)*256 + sub*8) = ov;
}

// ---------------- fused SpMM2 + MFMA GEMM ----------------
// Each wave owns 16 output rows (m-split): gathers its own y = L@x1 rows into
// a wave-private LDS slab (no __syncthreads anywhere), then computes
// out[b, rows, q] = bias + x0*(W0-W2) + x1*W1 + y*(2W2) via MFMA.
// B-frags read straight from wcb (24KB, L1/L2-resident).
// mfma_f32_16x16x32_bf16: A row=l&15, k=8*(l>>4)+i; C/D col=l&15, row=4*(l>>4)+reg.
// ylds row pitch 264 shorts (528B): bank advance 4/row -> ~2-way, free.
// x0c-in-d_out aliasing safe: wave reads x0c only for its own 16 rows and is
// the only writer of those out rows; per-wave program order orders them.

__global__ __launch_bounds__(256) void k_gemm_fused(
    const short* __restrict__ x0, const short* __restrict__ x1,
    const short* __restrict__ wcb, const float* __restrict__ bias,
    const int2* __restrict__ meta, const unsigned* __restrict__ rstart,
    const unsigned* __restrict__ rend, float* __restrict__ out){
  __shared__ short ylds[4][16*264];
  const int t = threadIdx.x, w = t>>6, l = t&63;
  const int half = l>>5, sub = l&31;
  const int vw = blockIdx.x*64 + w*16;
  short* const my = &ylds[w][0];
  const short* const src = x1;
  const int SROW = 256;
  const size_t off = (size_t)(sub>>4)*128 + (size_t)((sub&15)*8);

  // ---- phase 1: gather 16 y-rows (8 pairs, half-wave per row) ----
  for(int pr=0; pr<8; ++pr){
    const int vb = vw + pr*2;
    const unsigned sA = rstart[vb], sB = rstart[vb+1];
    const int nA = (int)(rend[vb]-sA), nB = (int)(rend[vb+1]-sB);
    const int nmax = (nA > nB) ? nA : nB;
    const unsigned s = half ? sB : sA;
    const int n = half ? nB : nA;
    SP_BODY
    *(u32x4*)(my + (pr*2+half)*264 + off) = ov;
  }

  // ---- phase 2: MFMA (wave-local; compiler orders LDS read-after-write) ----
  const int r = l&15, g = l>>4;
  f32x4 acc[4][4] = {};   // [batch][n]
#pragma unroll
  for(int c=0; c<6; ++c){
    const int part = c>>1, ko = (c&1)*32;
    const int kw = part*64 + ko + 8*g;
    const bf16x8 bfr0 = *(const bf16x8*)&wcb[( 0+r)*192 + kw];
    const bf16x8 bfr1 = *(const bf16x8*)&wcb[(16+r)*192 + kw];
    const bf16x8 bfr2 = *(const bf16x8*)&wcb[(32+r)*192 + kw];
    const bf16x8 bfr3 = *(const bf16x8*)&wcb[(48+r)*192 + kw];
#pragma unroll
    for(int bb=0; bb<4; ++bb){
      bf16x8 a;
      if(part==0)      a = *(const bf16x8*)(x0 + ((size_t)(bb>>1)*Vn + vw + r)*128 + (bb&1)*64 + ko + 8*g);
      else if(part==1) a = *(const bf16x8*)(x1 + ((size_t)(vw + r))*256 + bb*64 + ko + 8*g);
      else             a = *(const bf16x8*)(my + r*264 + bb*64 + ko + 8*g);
      acc[bb][0] = __builtin_amdgcn_mfma_f32_16x16x32_bf16(a, bfr0, acc[bb][0], 0, 0, 0);
      acc[bb][1] = __builtin_amdgcn_mfma_f32_16x16x32_bf16(a, bfr1, acc[bb][1], 0, 0, 0);
      acc[bb][2] = __builtin_amdgcn_mfma_f32_16x16x32_bf16(a, bfr2, acc[bb][2], 0, 0, 0);
      acc[bb][3] = __builtin_amdgcn_mfma_f32_16x16x32_bf16(a, bfr3, acc[bb][3], 0, 0, 0);
    }
  }

  // ---- epilogue ----
#pragma unroll
  for(int bb=0; bb<4; ++bb){
    float* ob = out + (size_t)bb*Vn*64;
#pragma unroll
    for(int n=0; n<4; ++n){
      const float bq = bias[n*16+r];
#pragma unroll
      for(int reg=0; reg<4; ++reg)
        ob[(size_t)(vw + g*4 + reg)*64 + n*16 + r] = acc[bb][n][reg] + bq;
    }
  }
}

// ---------------- launch ----------------

extern "C" void kernel_launch(void* const* d_in, const int* in_sizes, int n_in,
                              void* d_out, int out_size, void* d_ws, size_t ws_size,
                              hipStream_t stream){
  const float* lap_vals = (const float*)d_in[0];
  const float* x        = (const float*)d_in[1];
  const float* weight   = (const float*)d_in[2];
  const float* bias     = (const float*)d_in[3];
  const int*   lap_rows = (const int*)d_in[4];
  const int*   lap_cols = (const int*)d_in[5];
  float* out = (float*)d_out;
  short* x0c = (short*)d_out;   // bf16 x0 staged inside the output buffer

  char* w = (char*)d_ws;
  short* x1b = (short*)w;          w += (size_t)Vn*256*sizeof(short);
  int2* meta = (int2*)w;           w += (size_t)NNZn*8;
  unsigned* counts = (unsigned*)w; w += (size_t)Vn*4;
  unsigned* cursor = (unsigned*)w; w += (size_t)Vn*4;
  unsigned* rstart = (unsigned*)w; w += (size_t)Vn*4;
  unsigned* rend   = (unsigned*)w; w += (size_t)Vn*4;
  unsigned* bsums  = (unsigned*)w; w += 1024;
  short* wcb = (short*)w;          w += 12288*sizeof(short);

  k_zero<<<Vn/256, 256, 0, stream>>>(counts, Vn);
  k_pre<<<26352, 256, 0, stream>>>(lap_rows, counts, x, x0c, weight, wcb);
  k_scan_block<<<192, 1024, 0, stream>>>(counts, rend, bsums);
  k_scan_top<<<1, 256, 0, stream>>>(bsums);
  k_scan_add<<<Vn/256, 256, 0, stream>>>(counts, rend, bsums, rstart, cursor);
  k_scatter<<<NNZn/256, 256, 0, stream>>>(lap_vals, lap_rows, lap_cols, cursor, meta);

  // x1 = L @ x0   (gather from x0c: piece-split rows, 2 x 256B segments)
  k_spmm<128, (size_t)Vn*128><<<Vn/8, 256, 0, stream>>>(x0c, meta, rstart, rend, x1b);

  // fused: y-gather (L @ x1) + MFMA epilogue
  k_gemm_fused<<<Vn/64, 256, 0, stream>>>(x0c, x1b, wcb, bias,
                                          meta, rstart, rend, out);
}